// Round 4
// baseline (246.712 us; speedup 1.0000x reference)
//
#include <hip/hip_runtime.h>
#include <cmath>

// Outputs concatenated flat (all float32):
//   [0)      N*N*3 : dxyz_m
//   [N*N*3)  N*N   : buckets
//   [N*N*4)  N*N   : dscanid
//   [N*N*5)  N*N   : mask
//
// Strategy: mask density is ~0.3%, so ~99.7% of output bytes are zero.
// Dispatch 1: dense grid-stride f32x4 zero-fill (fill-order frontier, ~6.5 TB/s).
// Dispatch 2: compute-only pair kernel that stores ONLY masked entries.

#define TPB 256
#define JB  1024  // j's per block (x-dim)
#define II  12    // i-rows per block (3072/12 = 256 -> grid (3,256) = 768 blocks)

typedef float f32x4 __attribute__((ext_vector_type(4)));

__device__ __forceinline__ float bucket_base(float v) {
    // x = v / RES (RES=0.5 -> exact *2)
    const float x  = v * 2.0f;
    const float xa = fabsf(x);
    if (xa <= 2.0f) {
        // round-half-to-even like jnp.round
        return 8.0f + rintf(x);
    }
    // log path only when needed (xa>2 => x != 0)
    const float lr = logf(fmaxf(xa, 1e-6f) * 0.5f) / 2.0794415416798357f; // /log(8)
    const float sup = fminf(rintf(2.0f - 6.0f * lr), 8.0f);
    return 8.0f + ((x > 0.0f) ? sup : -sup);
}

__global__ __launch_bounds__(256) void zero_kernel(float* __restrict__ out,
                                                   size_t nvec4) {
    // Dense advancing frontier, same shape as rocclr fill (proven 6.6 TB/s).
    f32x4* o = reinterpret_cast<f32x4*>(out);
    const f32x4 z = {0.0f, 0.0f, 0.0f, 0.0f};
    const size_t stride = (size_t)gridDim.x * blockDim.x;
    for (size_t v = (size_t)blockIdx.x * blockDim.x + threadIdx.x; v < nvec4;
         v += stride)
        o[v] = z;
}

__global__ __launch_bounds__(256) void pair_sparse_kernel(
    const float* __restrict__ xyz, const int* __restrict__ grid,
    float* __restrict__ out, int N) {
#pragma clang fp contract(off)
    const int tid = threadIdx.x;
    const int w   = tid >> 6;   // wave id within block
    const int l   = tid & 63;   // lane
    const int jw0 = 256 * w;    // wave owns j-local [jw0, jw0+256)
    const int J0  = blockIdx.x * JB;
    const int I0  = blockIdx.y * II;

    // One-time per block: this thread's 4 j's -> registers (L2-resident loads,
    // amortized over II i-rows). No LDS, no barriers anywhere.
    float jx[4], jy[4], jz[4];
    int   jbat[4], jblk[4], jc0[4], jc1[4], jc2[4], xcj[4], ycj[4];
#pragma unroll
    for (int k = 0; k < 4; ++k) {
        const int j = J0 + jw0 + 64 * k + l;
        jx[k]   = xyz[3 * j + 0];
        jy[k]   = xyz[3 * j + 1];
        jz[k]   = xyz[3 * j + 2];
        jbat[k] = grid[5 * j + 0];
        jblk[k] = grid[5 * j + 1];
        jc0[k]  = grid[5 * j + 2];
        jc1[k]  = grid[5 * j + 3];
        jc2[k]  = grid[5 * j + 4];
        xcj[k]  = (int)ceilf(jx[k] / 3.0f);
        ycj[k]  = (int)ceilf(jy[k] / 3.0f);
    }

    const size_t NN = (size_t)N * (size_t)N;

    for (int ii = 0; ii < II; ++ii) {
        const int i = I0 + ii;

        // i-side is block-uniform -> scalar loads
        const float xi = xyz[3 * i + 0];
        const float yi = xyz[3 * i + 1];
        const float zi = xyz[3 * i + 2];
        const int bat_i = grid[5 * i + 0];
        const int blk_i = grid[5 * i + 1];
        const int c0i = grid[5 * i + 2];
        const int c1i = grid[5 * i + 3];
        const int c2i = grid[5 * i + 4];
        const int xci = (int)ceilf(xi / 3.0f);
        const int yci = (int)ceilf(yi / 3.0f);
        const int scan_i = blk_i >> 1;

        float dxm[4], dym[4], dzm[4];
        bool  mk[4];
        bool  any = false;
#pragma unroll
        for (int k = 0; k < 4; ++k) {
            const float dx = xi - jx[k];
            const float dy = yi - jy[k];
            const float dz = zi - jz[k];
            const bool batch_eq = (bat_i == jbat[k]);
            const bool block_le = (blk_i <= jblk[k]);
            const int  cadj = max(max(abs(c0i - jc0[k]), abs(c1i - jc1[k])),
                                  abs(c2i - jc2[k]));
            const bool forcekeep = (cadj <= 1) && (blk_i == jblk[k]);
            const bool keep_coarse =
                max(abs(xci - xcj[k]), abs(yci - ycj[k])) <= 1;
            const float d2 = dx * dx + dy * dy + dz * dz; // contract(off)
            const bool keepr = (d2 <= 9.0f);
            const bool m = batch_eq && block_le &&
                           (forcekeep || keep_coarse) && (forcekeep || keepr);
            mk[k] = m;
            any |= m;
            dxm[k] = dx;
            dym[k] = dy;
            dzm[k] = dz;
        }

        // Wave-uniform skip: ~42% of (i, 256j) units have no masked pair.
        if (__ballot(any ? 1 : 0) == 0ULL) continue;

        // Sparse stores: only masked lanes write (~0.3% of pairs).
#pragma unroll
        for (int k = 0; k < 4; ++k) {
            if (!mk[k]) continue;
            const int j = J0 + jw0 + 64 * k + l;
            const size_t base = (size_t)i * (size_t)N + (size_t)j;
            out[3 * base + 0] = dxm[k];
            out[3 * base + 1] = dym[k];
            out[3 * base + 2] = dzm[k];
            const float b0 = bucket_base(dxm[k]);
            const float b1 = bucket_base(dym[k]);
            const float b2 = bucket_base(dzm[k]);
            const float bsum = (289.0f * b0 + 17.0f * b1) + b2; // exact ints
            out[NN * 3 + base] = (float)(int)bsum;
            out[NN * 4 + base] = (float)((jblk[k] >> 1) - scan_i);
            out[NN * 5 + base] = 1.0f;
        }
    }
}

extern "C" void kernel_launch(void* const* d_in, const int* in_sizes, int n_in,
                              void* d_out, int out_size, void* d_ws, size_t ws_size,
                              hipStream_t stream) {
    const float* xyz  = (const float*)d_in[0];
    const int*   grid = (const int*)d_in[1];
    float*       out  = (float*)d_out;
    const int N = in_sizes[0] / 3; // xyz is (N,3); N=3072

    const size_t NN = (size_t)N * (size_t)N;
    const size_t nvec4 = NN * 6 / 4; // output floats / 4 (divisible)

    // Dispatch 1: dense zero-fill of the entire output region.
    zero_kernel<<<dim3(2048, 1, 1), dim3(TPB, 1, 1), 0, stream>>>(out, nvec4);

    // Dispatch 2: sparse writer (same stream -> ordered after the fill).
    dim3 gdim(N / JB, N / II, 1); // (3, 256) = 768 blocks
    pair_sparse_kernel<<<gdim, dim3(TPB, 1, 1), 0, stream>>>(xyz, grid, out, N);
}

// Round 5
// 220.418 us; speedup vs baseline: 1.1193x; 1.1193x over previous
//
#include <hip/hip_runtime.h>
#include <cmath>

// Outputs concatenated flat (all float32):
//   [0)      N*N*3 : dxyz_m
//   [N*N*3)  N*N   : buckets
//   [N*N*4)  N*N   : dscanid
//   [N*N*5)  N*N   : mask
//
// R5 = R1's proven store scheme (regular stores, wave-local LDS transpose for
// dxyz, float4 fast path) + register-resident j-side (no input staging, no
// __syncthreads) + II=4 i-rows per block. NO nontemporal stores (R3 showed
// they regress the write stream), NO pre-zero pass (R4 showed fill+sparse
// regresses vs fused single-pass writes).

#define TPB 256   // threads per block (4 waves)
#define JB  1024  // j's per block
#define II  4     // i-rows per block -> grid (3, 768)

typedef float f32x4 __attribute__((ext_vector_type(4)));

__device__ __forceinline__ float bucket_base(float v) {
    // x = v / RES (RES=0.5 -> exact *2)
    const float x  = v * 2.0f;
    const float xa = fabsf(x);
    if (xa <= 2.0f) {
        // round-half-to-even like jnp.round
        return 8.0f + rintf(x);
    }
    // log path only when needed (xa>2 => x != 0)
    const float lr = logf(fmaxf(xa, 1e-6f) * 0.5f) / 2.0794415416798357f; // /log(8)
    const float sup = fminf(rintf(2.0f - 6.0f * lr), 8.0f);
    return 8.0f + ((x > 0.0f) ? sup : -sup);
}

__global__ __launch_bounds__(256) void pair_kernel(
    const float* __restrict__ xyz, const int* __restrict__ grid,
    float* __restrict__ out, int N) {
#pragma clang fp contract(off)
    // Wave-local dxyz transpose staging only (each wave uses its own 3KB
    // quadrant; same-wave DS ordering -> no barrier needed anywhere).
    __shared__ float s_st[3 * JB];

    const int tid = threadIdx.x;
    const int w   = tid >> 6;   // wave id within block
    const int l   = tid & 63;   // lane
    const int jw0 = 256 * w;    // wave owns j-local [jw0, jw0+256)
    const int J0  = blockIdx.x * JB;
    const int I0  = blockIdx.y * II;

    // ---- One-time per block: this thread's 4 j's -> registers ----
    // j-local = jw0 + 64*k + l  (wave-contiguous layout for coalesced stores)
    float jx[4], jy[4], jz[4];
    int   jbat[4], jblk[4], jc0[4], jc1[4], jc2[4], xcj[4], ycj[4];
#pragma unroll
    for (int k = 0; k < 4; ++k) {
        const int j = J0 + jw0 + 64 * k + l;
        jx[k]   = xyz[3 * j + 0];
        jy[k]   = xyz[3 * j + 1];
        jz[k]   = xyz[3 * j + 2];
        jbat[k] = grid[5 * j + 0];
        jblk[k] = grid[5 * j + 1];
        jc0[k]  = grid[5 * j + 2];
        jc1[k]  = grid[5 * j + 3];
        jc2[k]  = grid[5 * j + 4];
        // per-j coarse cell computed ONCE per block (was per (i,j) in R1)
        xcj[k] = (int)ceilf(jx[k] / 3.0f);
        ycj[k] = (int)ceilf(jy[k] / 3.0f);
    }

    const size_t NN = (size_t)N * (size_t)N;

    for (int ii = 0; ii < II; ++ii) {
        const int i = I0 + ii;

        // i-side is block-uniform -> scalar loads
        const float xi = xyz[3 * i + 0];
        const float yi = xyz[3 * i + 1];
        const float zi = xyz[3 * i + 2];
        const int bat_i = grid[5 * i + 0];
        const int blk_i = grid[5 * i + 1];
        const int c0i = grid[5 * i + 2];
        const int c1i = grid[5 * i + 3];
        const int c2i = grid[5 * i + 4];
        const int xci = (int)ceilf(xi / 3.0f);
        const int yci = (int)ceilf(yi / 3.0f);
        const int scan_i = blk_i >> 1;

        float dxm[4], dym[4], dzm[4];
        bool  mk[4];
        bool  any = false;
#pragma unroll
        for (int k = 0; k < 4; ++k) {
            const float dx = xi - jx[k];
            const float dy = yi - jy[k];
            const float dz = zi - jz[k];
            const bool batch_eq = (bat_i == jbat[k]);
            const bool block_le = (blk_i <= jblk[k]);
            const int  cadj = max(max(abs(c0i - jc0[k]), abs(c1i - jc1[k])),
                                  abs(c2i - jc2[k]));
            const bool forcekeep = (cadj <= 1) && (blk_i == jblk[k]);
            const bool keep_coarse =
                max(abs(xci - xcj[k]), abs(yci - ycj[k])) <= 1;
            const float d2 = dx * dx + dy * dy + dz * dz; // contract(off)
            const bool keepr = (d2 <= 9.0f);
            const bool m = batch_eq && block_le &&
                           (forcekeep || keep_coarse) && (forcekeep || keepr);
            mk[k] = m;
            any |= m;
            dxm[k] = m ? dx : 0.0f;
            dym[k] = m ? dy : 0.0f;
            dzm[k] = m ? dz : 0.0f;
        }

        const size_t rowbase = (size_t)i * (size_t)N + (size_t)J0;
        float* __restrict__ obkt = out + NN * 3 + rowbase;
        float* __restrict__ odsc = out + NN * 4 + rowbase;
        float* __restrict__ omsk = out + NN * 5 + rowbase;
        // wave's spans are 16B-aligned (rowbase, jw0 multiples of 256)
        f32x4* __restrict__ od4 =
            reinterpret_cast<f32x4*>(out + 3 * (rowbase + (size_t)jw0));
        f32x4* __restrict__ ob4 = reinterpret_cast<f32x4*>(obkt + jw0);
        f32x4* __restrict__ os4 = reinterpret_cast<f32x4*>(odsc + jw0);
        f32x4* __restrict__ om4 = reinterpret_cast<f32x4*>(omsk + jw0);

        // ---- Wave-uniform fast path: whole wave empty -> packed zeros ----
        if (__ballot(any ? 1 : 0) == 0ULL) {
            const f32x4 z4 = {0.0f, 0.0f, 0.0f, 0.0f};
#pragma unroll
            for (int p = 0; p < 3; ++p) od4[64 * p + l] = z4;
            ob4[l] = z4;
            os4[l] = z4;
            om4[l] = z4;
            continue;
        }

        // ---- Slow path: dword stores (lane-contiguous) + dxyz transpose ----
#pragma unroll
        for (int k = 0; k < 4; ++k) {
            const int jl = jw0 + 64 * k + l;
            float b = 0.0f, d = 0.0f, mvf = 0.0f;
            if (mk[k]) {
                const float b0 = bucket_base(dxm[k]);
                const float b1 = bucket_base(dym[k]);
                const float b2 = bucket_base(dzm[k]);
                const float bsum = (289.0f * b0 + 17.0f * b1) + b2; // exact ints
                b   = (float)(int)bsum;
                d   = (float)((jblk[k] >> 1) - scan_i);
                mvf = 1.0f;
            }
            obkt[jl] = b;
            odsc[jl] = d;
            omsk[jl] = mvf;
            // wave-private LDS staging (stride-12B: 2-way aliasing, ~free)
            s_st[3 * jl + 0] = dxm[k];
            s_st[3 * jl + 1] = dym[k];
            s_st[3 * jl + 2] = dzm[k];
        }

        // Wave-local transpose readback -> 3 fully-coalesced 1024B stores.
        // Same-wave DS ordering (lgkmcnt) -> no barrier needed.
        const f32x4* st4 = reinterpret_cast<const f32x4*>(s_st + 3 * jw0);
#pragma unroll
        for (int p = 0; p < 3; ++p) od4[64 * p + l] = st4[64 * p + l];
    }
}

extern "C" void kernel_launch(void* const* d_in, const int* in_sizes, int n_in,
                              void* d_out, int out_size, void* d_ws, size_t ws_size,
                              hipStream_t stream) {
    const float* xyz  = (const float*)d_in[0];
    const int*   grid = (const int*)d_in[1];
    float*       out  = (float*)d_out;
    const int N = in_sizes[0] / 3; // xyz is (N,3); N=3072

    dim3 gdim(N / JB, N / II, 1); // (3, 768)
    pair_kernel<<<gdim, dim3(TPB, 1, 1), 0, stream>>>(xyz, grid, out, N);
}